// Round 1
// 295.424 us; speedup vs baseline: 1.4380x; 1.4380x over previous
//
#include <hip/hip_runtime.h>

// HiearchicalFFTShiftModel: closed-form spectrum with EXACT emulation of the
// reference's complex64 phase quantization, + 3-pass 2^24 complex IFFT (c2r packing).
//
// Round-1 changes vs 424.6us baseline:
//  1. build_q: the chain product over stages 1..17 depends only on k mod 2^18.
//     Precompute Q[2^18] (2 MB, lives in the first 2 MB of d_out, which is free
//     until stage A). Main build_w starts from Q[k&0x3FFFF] and does stages
//     18..23 only: 26 sincos/thread -> 9.  Float-op sequence per k is
//     bit-identical to the previous kernel (same order/rounding).
//  2. FFT stages: radix-2 level pairs fused into radix-4 butterflies (same
//     dataflow -> same bit-reversal permutation). LDS ops 256->128/wave,
//     barriers 9->5, twiddles 8 sincos -> 3 sincos + tw^2 squaring.
//     Per-step thread->quad mappings keep every ds_read_b64 at the
//     4-lane/bank-pair floor (mod-16 residue spread verified per step).
//  3. Stage B/C load twiddles are arithmetic progressions per thread ->
//     2 sincos + rotation recurrence instead of 16 sincos.

constexpr float PI_F    = 3.14159265358979323846f;
constexpr float TWOPI_F = 6.28318530717958647692f;
constexpr unsigned M24 = 1u << 24;

__device__ __forceinline__ void phase_sincos(float th, float* sn, float* cs) {
    // Accurate sin/cos of the float32 value th (|th| up to ~1.1e8):
    // reduce mod 2*pi in double, evaluate in float.
    double d = (double)th * 0.15915494309189533577;  // 1/(2*pi)
    d -= rint(d);                                    // frac in [-0.5, 0.5]
    float ang = (float)(d * 6.2831853071795864769);  // [-pi, pi]
    __sincosf(ang, sn, cs);
}

// ---------------- Kernel Q: partial chain product over stages 1..17 ----------------
// Q[r] = T_{ctz(r)} * prod_{i=ctz(r)+1}^{17} F_i(sd_i(r))   for r in [1, 2^18)
// Exactly the same float-op sequence as the old build_w loop for i<=17.
__global__ __launch_bounds__(256) void build_q(const float* __restrict__ el,
                                               float2* __restrict__ Q) {
    __shared__ float c_s[18], s_s[18], T_s[18];
    int tid = threadIdx.x;
    if (tid < 18) {
        float e = el[tid];
        float shift1 = e * (1.0f / (float)(1u << tid));   // exact (pow2 scale)
        float sh2 = 1.0f - shift1;                        // THE float32 rounding
        float s = sh2 * (float)(1u << tid);               // exact
        float c = (float)(6.2831853071795864769 / (double)((1u << tid) + 1u));
        c_s[tid] = c;
        s_s[tid] = s;
        float p  = (float)(1u << tid) * c;                // exact pow2 scale
        float th = p * s;                                 // fl32
        float sn, cs; phase_sincos(th, &sn, &cs);
        T_s[tid] = cs;                                    // terminal nyquist value
    }
    __syncthreads();

    unsigned r = blockIdx.x * 256u + (unsigned)tid;       // [0, 2^18)
    if (r == 0u) { Q[0] = make_float2(1.0f, 0.0f); return; }

    unsigned t = (unsigned)__builtin_ctz(r);              // t <= 17
    float Pr = T_s[t], Pi = 0.0f;

#pragma unroll
    for (int i = 1; i <= 17; ++i) {
        unsigned hi = 1u << i;
        int sd = (int)((r + hi) & (2u * hi - 1u)) - (int)hi;
        int K  = (i <= (int)t) ? 0 : (sd < 0 ? -sd : sd);
        float sgn = (sd < 0) ? -1.0f : 1.0f;
        float p  = (float)K * c_s[i];                     // fl32(K*c_i)
        float th = p * s_s[i];                            // fl32(.. * s_i)
        float sn, cs; phase_sincos(th, &sn, &cs);
        float ssn = sgn * sn;
        float nr = Pr * cs - Pi * ssn;
        float ni = Pr * ssn + Pi * cs;
        Pr = nr; Pi = ni;
    }
    Q[r] = make_float2(Pr, Pi);
}

// ---------------- Kernel A: build W[k] (packed c2r spectrum), scaled by 1/N ----------------
__global__ __launch_bounds__(256) void build_w(const float* __restrict__ el,
                                               const float2* __restrict__ Q,
                                               float2* __restrict__ W) {
    __shared__ float c_s[25], s_s[25], T_s[24];
    int tid = threadIdx.x;
    if (tid < 25) {
        float e = el[tid];
        float shift1 = e * (1.0f / (float)(1u << tid));   // exact (pow2 scale)
        float sh2 = 1.0f - shift1;                        // THE float32 rounding
        float s = sh2 * (float)(1u << tid);               // exact
        float c = (float)(6.2831853071795864769 / (double)((1u << tid) + 1u));
        c_s[tid] = c;
        s_s[tid] = s;
        if (tid < 24) {
            float p  = (float)(1u << tid) * c;            // exact pow2 scale
            float th = p * s;                             // fl32
            float sn, cs; phase_sincos(th, &sn, &cs);
            T_s[tid] = cs;                                // terminal nyquist value
        }
    }
    __syncthreads();

    unsigned k = blockIdx.x * 256u + (unsigned)tid;
    if (k > 8388608u) return;                             // k in [0, 2^23]

    const float sc = 1.0f / 33554432.0f;                  // 1/N

    if (k == 0u) {
        // S[0]=1 ; S[m]=cos(theta_24(2^24))
        float p  = 16777216.0f * c_s[24];                 // exact pow2 scale
        float th = p * s_s[24];
        float sn, cs; phase_sincos(th, &sn, &cs);
        float Smr = cs;
        W[0] = make_float2((1.0f + Smr) * sc, (1.0f - Smr) * sc);
        return;
    }

    unsigned t = (unsigned)__builtin_ctz(k);              // t <= 23
    unsigned r = k & 0x3FFFFu;                            // k mod 2^18
    float Pr, Pi;
    if (r != 0u) {
        float2 q = Q[r];                                  // stages 1..17 precomputed
        Pr = q.x; Pi = q.y;
    } else {
        Pr = T_s[t]; Pi = 0.0f;                           // t >= 18 here
    }

#pragma unroll
    for (int i = 18; i <= 23; ++i) {
        unsigned hi = 1u << i;
        int sd = (int)((k + hi) & (2u * hi - 1u)) - (int)hi;
        int K  = (i <= (int)t) ? 0 : (sd < 0 ? -sd : sd); // identity factor if i<=t
        float sgn = (sd < 0) ? -1.0f : 1.0f;
        float p  = (float)K * c_s[i];                     // fl32(K*c_i)
        float th = p * s_s[i];                            // fl32(.. * s_i)
        float sn, cs; phase_sincos(th, &sn, &cs);
        float ssn = sgn * sn;
        float nr = Pr * cs - Pi * ssn;
        float ni = Pr * ssn + Pi * cs;
        Pr = nr; Pi = ni;
    }

    // level 24 factors (indices are the raw bins, never folded, sign +)
    unsigned mk = M24 - k;
    float thk = ((float)k  * c_s[24]) * s_s[24];
    float thm = ((float)mk * c_s[24]) * s_s[24];
    float snk, csk, snm, csm;
    phase_sincos(thk, &snk, &csk);
    phase_sincos(thm, &snm, &csm);

    float Skr = Pr * csk - Pi * snk;
    float Ski = Pr * snk + Pi * csk;
    float Smr = Pr * csm + Pi * snm;                      // conj(P) * e^{i*thm}
    float Smi = Pr * snm - Pi * csm;

    // c2r packing
    float Ar = Skr + Smr, Ai = Ski - Smi;
    float Br = Skr - Smr, Bi = Ski + Smi;
    float ang = (float)k * (TWOPI_F / 33554432.0f);       // 2*pi*k/N in [0, pi/2]
    float ts, tc; __sincosf(ang, &ts, &tc);
    float Cr = tc * Br - ts * Bi;
    float Ci = ts * Br + tc * Bi;

    W[k] = make_float2((Ar - Ci) * sc, (Ai + Cr) * sc);
    if (k != 8388608u)
        W[mk] = make_float2((Ar + Ci) * sc, (Cr - Ai) * sc);
}

// ---------------- radix-4 butterfly (fused radix-2 level pair h, h/2) ----------------
// Elements e0, e0+d, e0+2d, e0+3d with d = h/2; tw = e^{+i*pi*j2/h}.
// Level h:   (e0,e2) tw ; (e1,e3) i*tw.   Level h/2: (e0,e1) and (e2,e3) tw^2.
__device__ __forceinline__ void bf4(float2* __restrict__ row, int e0, int d,
                                    float2 tw, float2 tw2) {
    float2 x0 = row[e0], x1 = row[e0 + d], x2 = row[e0 + 2*d], x3 = row[e0 + 3*d];
    float2 a0 = make_float2(x0.x + x2.x, x0.y + x2.y);
    float2 d0 = make_float2(x0.x - x2.x, x0.y - x2.y);
    float2 a1 = make_float2(x1.x + x3.x, x1.y + x3.y);
    float2 d1 = make_float2(x1.x - x3.x, x1.y - x3.y);
    float2 a2 = make_float2(d0.x * tw.x - d0.y * tw.y,  d0.x * tw.y + d0.y * tw.x);
    float2 a3 = make_float2(-d1.x * tw.y - d1.y * tw.x, d1.x * tw.x - d1.y * tw.y);
    row[e0]       = make_float2(a0.x + a1.x, a0.y + a1.y);
    float2 u1 = make_float2(a0.x - a1.x, a0.y - a1.y);
    row[e0 + d]   = make_float2(u1.x * tw2.x - u1.y * tw2.y, u1.x * tw2.y + u1.y * tw2.x);
    row[e0 + 2*d] = make_float2(a2.x + a3.x, a2.y + a3.y);
    float2 u3 = make_float2(a2.x - a3.x, a2.y - a3.y);
    row[e0 + 3*d] = make_float2(u3.x * tw2.x - u3.y * tw2.y, u3.x * tw2.y + u3.y * tw2.x);
}

// ---------------- shared radix-4 in-place DIF inverse FFT over 16 rows x 256 ----------------
// Dataflow identical to 8 radix-2 levels -> output bit-reversed within each row
// (position p holds X[brev8(p)]), exactly as before.
__device__ __forceinline__ void fft256x16_inv(float2 (*lds)[257], int tid) {
    // step0: h=128, d=64.  j2 = tid&63 (1 sincos), row uniform per wave.
    {
        int j2 = tid & 63;
        float s, c; __sincosf((PI_F / 128.0f) * (float)j2, &s, &c);
        float2 tw  = make_float2(c, s);
        float2 tw2 = make_float2(c * c - s * s, 2.0f * c * s);
        __syncthreads();
#pragma unroll
        for (int v = 0; v < 4; ++v) {
            int row = (tid >> 6) + 4 * v;
            bf4(lds[row], j2, 64, tw, tw2);
        }
    }
    // step1: h=32, d=16.  row = tid&15, j2 = tid>>4, bb = v.
    {
        int rowb = tid & 15;
        int j2   = tid >> 4;                 // [0,16)
        float s, c; __sincosf((PI_F / 32.0f) * (float)j2, &s, &c);
        float2 tw  = make_float2(c, s);
        float2 tw2 = make_float2(c * c - s * s, 2.0f * c * s);
        __syncthreads();
#pragma unroll
        for (int v = 0; v < 4; ++v) {
            bf4(lds[rowb], 64 * v + j2, 16, tw, tw2);
        }
    }
    // step2: h=8, d=4.  row = tid&15, j2 = tid>>6, bb = (tid>>4)&3 | v<<2.
    {
        int rowb = tid & 15;
        int j2   = tid >> 6;                 // [0,4), wave-uniform
        int bbl  = (tid >> 4) & 3;
        float s, c; __sincosf((PI_F / 8.0f) * (float)j2, &s, &c);
        float2 tw  = make_float2(c, s);
        float2 tw2 = make_float2(c * c - s * s, 2.0f * c * s);
        __syncthreads();
#pragma unroll
        for (int v = 0; v < 4; ++v) {
            int bb = bbl + 4 * v;
            bf4(lds[rowb], 16 * bb + j2, 4, tw, tw2);
        }
    }
    // step3: h=2, d=1.  j2=0 -> tw=1, i*tw=i, tw2=1 (all twiddles trivial).
    {
        int rowb = tid & 15;
        int bbl  = tid >> 4;                 // [0,16)
        __syncthreads();
#pragma unroll
        for (int v = 0; v < 4; ++v) {
            int e0 = 4 * (bbl + 16 * v);
            float2* row = lds[rowb];
            float2 x0 = row[e0], x1 = row[e0 + 1], x2 = row[e0 + 2], x3 = row[e0 + 3];
            float2 a0 = make_float2(x0.x + x2.x, x0.y + x2.y);
            float2 d0 = make_float2(x0.x - x2.x, x0.y - x2.y);
            float2 a1 = make_float2(x1.x + x3.x, x1.y + x3.y);
            float2 d1 = make_float2(x1.x - x3.x, x1.y - x3.y);
            row[e0]     = make_float2(a0.x + a1.x, a0.y + a1.y);
            row[e0 + 1] = make_float2(a0.x - a1.x, a0.y - a1.y);
            row[e0 + 2] = make_float2(d0.x - d1.y, d0.y + d1.x);   // a2 + i*d1
            row[e0 + 3] = make_float2(d0.x + d1.y, d0.y - d1.x);   // a2 - i*d1
        }
    }
    __syncthreads();
}

// ---------------- Stage A: IDFT over k3 (stride 65536) ----------------
__global__ __launch_bounds__(256) void fft_stage_a(const float2* __restrict__ in,
                                                   float2* __restrict__ out) {
    __shared__ float2 lds[16][257];
    int tid   = threadIdx.x;
    int cbase = blockIdx.x * 16;           // c = k1 + 256*k2, 16 consecutive per WG
#pragma unroll
    for (int u = 0; u < 16; ++u) {
        int e = tid + 256 * u;
        int row = e & 15, k3 = e >> 4;
        lds[row][k3] = in[cbase + row + (k3 << 16)];
    }
    fft256x16_inv(lds, tid);
#pragma unroll
    for (int u = 0; u < 16; ++u) {
        int e = tid + 256 * u;
        int row = e & 15, p = e >> 4;
        int t3 = (int)(__brev((unsigned)p) >> 24);
        out[cbase + row + (t3 << 16)] = lds[row][p];
    }
}

// ---------------- Stage B: twiddle e^{2*pi*i*t3*k2/65536}, IDFT over k2 (stride 256) ----------------
__global__ __launch_bounds__(256) void fft_stage_b(const float2* __restrict__ in,
                                                   float2* __restrict__ out) {
    __shared__ float2 lds[16][257];
    int tid = threadIdx.x;
    int wg  = blockIdx.x;
    int k1b = (wg & 15) * 16;
    int t3  = wg >> 4;
    const float tsc = TWOPI_F / 65536.0f;

    // Per thread: row = tid&15 fixed, k2 = (tid>>4) + 16u -> twiddle angles are an
    // arithmetic progression: 2 sincos + rotation recurrence instead of 16 sincos.
    {
        int row = tid & 15;
        int k20 = tid >> 4;
        float sb, cb; __sincosf(tsc * (float)(t3 * k20), &sb, &cb);
        float ss, cs; __sincosf(tsc * (float)(t3 * 16), &ss, &cs);
        float2 w = make_float2(cb, sb);
#pragma unroll
        for (int u = 0; u < 16; ++u) {
            int k2 = k20 + 16 * u;
            float2 v = in[k1b + row + (k2 << 8) + (t3 << 16)];
            lds[row][k2] = make_float2(v.x * w.x - v.y * w.y, v.x * w.y + v.y * w.x);
            float nx = w.x * cs - w.y * ss;
            float ny = w.x * ss + w.y * cs;
            w = make_float2(nx, ny);
        }
    }
    fft256x16_inv(lds, tid);
#pragma unroll
    for (int u = 0; u < 16; ++u) {
        int e = tid + 256 * u;
        int row = e & 15, p = e >> 4;
        int t2 = (int)(__brev((unsigned)p) >> 24);
        out[k1b + row + (t2 << 8) + (t3 << 16)] = lds[row][p];
    }
}

// ---------------- Stage C: twiddle e^{2*pi*i*(t3+256*t2)*k1/2^24}, IDFT over k1 (stride 1) ----------------
__global__ __launch_bounds__(256) void fft_stage_c(const float2* __restrict__ in,
                                                   float2* __restrict__ out) {
    __shared__ float2 lds[16][257];
    int tid = threadIdx.x;
    int wg  = blockIdx.x;
    int t3b = (wg & 15) * 16;
    int t2  = wg >> 4;
    const float tsc = TWOPI_F / 16777216.0f;

    // Per thread: k1 = tid fixed, r = u -> angle = tsc*(base + u*k1):
    // 2 sincos + rotation recurrence instead of 16 sincos.
    {
        int k1 = tid;
        int base = (t3b + (t2 << 8)) * k1;          // < 2^24, exact in float
        float sb, cb; __sincosf(tsc * (float)base, &sb, &cb);
        float ss, cs; __sincosf(tsc * (float)k1, &ss, &cs);
        float2 w = make_float2(cb, sb);
#pragma unroll
        for (int u = 0; u < 16; ++u) {
            float2 v = in[k1 + (t2 << 8) + ((t3b + u) << 16)];
            lds[u][k1] = make_float2(v.x * w.x - v.y * w.y, v.x * w.y + v.y * w.x);
            float nx = w.x * cs - w.y * ss;
            float ny = w.x * ss + w.y * cs;
            w = make_float2(nx, ny);
        }
    }
    fft256x16_inv(lds, tid);
#pragma unroll
    for (int u = 0; u < 16; ++u) {
        int e = tid + 256 * u;
        int r = e & 15, p = e >> 4;
        int t1 = (int)(__brev((unsigned)p) >> 24);
        out[(t3b + r) + (t2 << 8) + (t1 << 16)] = lds[r][p];
    }
}

extern "C" void kernel_launch(void* const* d_in, const int* in_sizes, int n_in,
                              void* d_out, int out_size, void* d_ws, size_t ws_size,
                              hipStream_t stream) {
    const float* el = (const float*)d_in[0];   // 25 floats
    float2* W  = (float2*)d_ws;                // 2^24 float2 = 128 MiB scratch
    float2* Gd = (float2*)d_out;               // out buffer doubles as complex ping-pong
    float2* Q  = (float2*)d_out;               // Q table (2 MiB) lives in out until stage A

    // build_q (out[0:2MB]) -> build_w (ws) -> stageA: ws->out (clobbers Q, ok)
    // -> stageB: out->ws -> stageC: ws->out (final real signal)
    hipLaunchKernelGGL(build_q,     dim3(1024),  dim3(256), 0, stream, el, Q);
    hipLaunchKernelGGL(build_w,     dim3(32769), dim3(256), 0, stream, el, Q, W);
    hipLaunchKernelGGL(fft_stage_a, dim3(4096),  dim3(256), 0, stream, W, Gd);
    hipLaunchKernelGGL(fft_stage_b, dim3(4096),  dim3(256), 0, stream, Gd, W);
    hipLaunchKernelGGL(fft_stage_c, dim3(4096),  dim3(256), 0, stream, W, Gd);
}

// Round 2
// 288.477 us; speedup vs baseline: 1.4727x; 1.0241x over previous
//
#include <hip/hip_runtime.h>

// HiearchicalFFTShiftModel: closed-form spectrum with EXACT emulation of the
// reference's complex64 phase quantization, + 3-pass 2^24 complex IFFT (c2r packing).
//
// Round-2 change vs 295us: fuse build_w INTO fft_stage_a. W is never written to
// HBM (saves 132 MB write + 128 MB read). To keep the (k, 2^24-k) chain pairing,
// each block owns 8 consecutive columns c=8b..8b+7 AND their mirrors 65536-c;
// each chain fills lds[r][k3] and lds[r^8][255-k3]. Block 0 handles the
// self-mirrored c=0 / c=32768 rows. Chain float-op sequence is bit-identical
// to the previous build_w, so the output is bit-identical.

constexpr float PI_F    = 3.14159265358979323846f;
constexpr float TWOPI_F = 6.28318530717958647692f;
constexpr unsigned M24 = 1u << 24;

__device__ __forceinline__ void phase_sincos(float th, float* sn, float* cs) {
    // Accurate sin/cos of the float32 value th (|th| up to ~1.1e8):
    // reduce mod 2*pi in double, evaluate in float.
    double d = (double)th * 0.15915494309189533577;  // 1/(2*pi)
    d -= rint(d);                                    // frac in [-0.5, 0.5]
    float ang = (float)(d * 6.2831853071795864769);  // [-pi, pi]
    __sincosf(ang, sn, cs);
}

// ---------------- Kernel Q: partial chain product over stages 1..17 ----------------
// Q[r] = T_{ctz(r)} * prod_{i=ctz(r)+1}^{17} F_i(sd_i(r))   for r in [1, 2^18)
__global__ __launch_bounds__(256) void build_q(const float* __restrict__ el,
                                               float2* __restrict__ Q) {
    __shared__ float c_s[18], s_s[18], T_s[18];
    int tid = threadIdx.x;
    if (tid < 18) {
        float e = el[tid];
        float shift1 = e * (1.0f / (float)(1u << tid));   // exact (pow2 scale)
        float sh2 = 1.0f - shift1;                        // THE float32 rounding
        float s = sh2 * (float)(1u << tid);               // exact
        float c = (float)(6.2831853071795864769 / (double)((1u << tid) + 1u));
        c_s[tid] = c;
        s_s[tid] = s;
        float p  = (float)(1u << tid) * c;                // exact pow2 scale
        float th = p * s;                                 // fl32
        float sn, cs; phase_sincos(th, &sn, &cs);
        T_s[tid] = cs;                                    // terminal nyquist value
    }
    __syncthreads();

    unsigned r = blockIdx.x * 256u + (unsigned)tid;       // [0, 2^18)
    if (r == 0u) { Q[0] = make_float2(1.0f, 0.0f); return; }

    unsigned t = (unsigned)__builtin_ctz(r);              // t <= 17
    float Pr = T_s[t], Pi = 0.0f;

#pragma unroll
    for (int i = 1; i <= 17; ++i) {
        unsigned hi = 1u << i;
        int sd = (int)((r + hi) & (2u * hi - 1u)) - (int)hi;
        int K  = (i <= (int)t) ? 0 : (sd < 0 ? -sd : sd);
        float sgn = (sd < 0) ? -1.0f : 1.0f;
        float p  = (float)K * c_s[i];                     // fl32(K*c_i)
        float th = p * s_s[i];                            // fl32(.. * s_i)
        float sn, cs; phase_sincos(th, &sn, &cs);
        float ssn = sgn * sn;
        float nr = Pr * cs - Pi * ssn;
        float ni = Pr * ssn + Pi * cs;
        Pr = nr; Pi = ni;
    }
    Q[r] = make_float2(Pr, Pi);
}

// ---------------- chain: W[k] and W[2^24-k] for k in [1, 2^23] ----------------
// Bit-identical port of the old build_w body (stages 18..23 + level 24 + c2r pack).
struct WPair { float2 wk, wmk; };

__device__ __forceinline__ WPair chain_W(unsigned k,
                                         const float* __restrict__ c_s,
                                         const float* __restrict__ s_s,
                                         const float* __restrict__ T_s,
                                         const float2* __restrict__ Q) {
    const float sc = 1.0f / 33554432.0f;                  // 1/N
    unsigned t = (unsigned)__builtin_ctz(k);              // t <= 23
    unsigned r = k & 0x3FFFFu;                            // k mod 2^18
    float Pr, Pi;
    if (r != 0u) {
        float2 q = Q[r];                                  // stages 1..17 precomputed
        Pr = q.x; Pi = q.y;
    } else {
        Pr = T_s[t]; Pi = 0.0f;                           // t >= 18 here
    }

#pragma unroll
    for (int i = 18; i <= 23; ++i) {
        unsigned hi = 1u << i;
        int sd = (int)((k + hi) & (2u * hi - 1u)) - (int)hi;
        int K  = (i <= (int)t) ? 0 : (sd < 0 ? -sd : sd); // identity factor if i<=t
        float sgn = (sd < 0) ? -1.0f : 1.0f;
        float p  = (float)K * c_s[i];                     // fl32(K*c_i)
        float th = p * s_s[i];                            // fl32(.. * s_i)
        float sn, cs; phase_sincos(th, &sn, &cs);
        float ssn = sgn * sn;
        float nr = Pr * cs - Pi * ssn;
        float ni = Pr * ssn + Pi * cs;
        Pr = nr; Pi = ni;
    }

    // level 24 factors (indices are the raw bins, never folded, sign +)
    unsigned mk = M24 - k;
    float thk = ((float)k  * c_s[24]) * s_s[24];
    float thm = ((float)mk * c_s[24]) * s_s[24];
    float snk, csk, snm, csm;
    phase_sincos(thk, &snk, &csk);
    phase_sincos(thm, &snm, &csm);

    float Skr = Pr * csk - Pi * snk;
    float Ski = Pr * snk + Pi * csk;
    float Smr = Pr * csm + Pi * snm;                      // conj(P) * e^{i*thm}
    float Smi = Pr * snm - Pi * csm;

    // c2r packing
    float Ar = Skr + Smr, Ai = Ski - Smi;
    float Br = Skr - Smr, Bi = Ski + Smi;
    float ang = (float)k * (TWOPI_F / 33554432.0f);
    float ts, tc; __sincosf(ang, &ts, &tc);
    float Cr = tc * Br - ts * Bi;
    float Ci = ts * Br + tc * Bi;

    WPair w;
    w.wk  = make_float2((Ar - Ci) * sc, (Ai + Cr) * sc);
    w.wmk = make_float2((Ar + Ci) * sc, (Cr - Ai) * sc);
    return w;
}

// ---------------- radix-4 butterfly (fused radix-2 level pair h, h/2) ----------------
__device__ __forceinline__ void bf4(float2* __restrict__ row, int e0, int d,
                                    float2 tw, float2 tw2) {
    float2 x0 = row[e0], x1 = row[e0 + d], x2 = row[e0 + 2*d], x3 = row[e0 + 3*d];
    float2 a0 = make_float2(x0.x + x2.x, x0.y + x2.y);
    float2 d0 = make_float2(x0.x - x2.x, x0.y - x2.y);
    float2 a1 = make_float2(x1.x + x3.x, x1.y + x3.y);
    float2 d1 = make_float2(x1.x - x3.x, x1.y - x3.y);
    float2 a2 = make_float2(d0.x * tw.x - d0.y * tw.y,  d0.x * tw.y + d0.y * tw.x);
    float2 a3 = make_float2(-d1.x * tw.y - d1.y * tw.x, d1.x * tw.x - d1.y * tw.y);
    row[e0]       = make_float2(a0.x + a1.x, a0.y + a1.y);
    float2 u1 = make_float2(a0.x - a1.x, a0.y - a1.y);
    row[e0 + d]   = make_float2(u1.x * tw2.x - u1.y * tw2.y, u1.x * tw2.y + u1.y * tw2.x);
    row[e0 + 2*d] = make_float2(a2.x + a3.x, a2.y + a3.y);
    float2 u3 = make_float2(a2.x - a3.x, a2.y - a3.y);
    row[e0 + 3*d] = make_float2(u3.x * tw2.x - u3.y * tw2.y, u3.x * tw2.y + u3.y * tw2.x);
}

// ---------------- shared radix-4 in-place DIF inverse FFT over 16 rows x 256 ----------------
// Output lands bit-reversed within each row: position p holds X[brev8(p)].
__device__ __forceinline__ void fft256x16_inv(float2 (*lds)[257], int tid) {
    // step0: h=128, d=64.
    {
        int j2 = tid & 63;
        float s, c; __sincosf((PI_F / 128.0f) * (float)j2, &s, &c);
        float2 tw  = make_float2(c, s);
        float2 tw2 = make_float2(c * c - s * s, 2.0f * c * s);
        __syncthreads();
#pragma unroll
        for (int v = 0; v < 4; ++v) {
            int row = (tid >> 6) + 4 * v;
            bf4(lds[row], j2, 64, tw, tw2);
        }
    }
    // step1: h=32, d=16.
    {
        int rowb = tid & 15;
        int j2   = tid >> 4;
        float s, c; __sincosf((PI_F / 32.0f) * (float)j2, &s, &c);
        float2 tw  = make_float2(c, s);
        float2 tw2 = make_float2(c * c - s * s, 2.0f * c * s);
        __syncthreads();
#pragma unroll
        for (int v = 0; v < 4; ++v) {
            bf4(lds[rowb], 64 * v + j2, 16, tw, tw2);
        }
    }
    // step2: h=8, d=4.
    {
        int rowb = tid & 15;
        int j2   = tid >> 6;
        int bbl  = (tid >> 4) & 3;
        float s, c; __sincosf((PI_F / 8.0f) * (float)j2, &s, &c);
        float2 tw  = make_float2(c, s);
        float2 tw2 = make_float2(c * c - s * s, 2.0f * c * s);
        __syncthreads();
#pragma unroll
        for (int v = 0; v < 4; ++v) {
            int bb = bbl + 4 * v;
            bf4(lds[rowb], 16 * bb + j2, 4, tw, tw2);
        }
    }
    // step3: h=2, d=1.  all twiddles trivial.
    {
        int rowb = tid & 15;
        int bbl  = tid >> 4;
        __syncthreads();
#pragma unroll
        for (int v = 0; v < 4; ++v) {
            int e0 = 4 * (bbl + 16 * v);
            float2* row = lds[rowb];
            float2 x0 = row[e0], x1 = row[e0 + 1], x2 = row[e0 + 2], x3 = row[e0 + 3];
            float2 a0 = make_float2(x0.x + x2.x, x0.y + x2.y);
            float2 d0 = make_float2(x0.x - x2.x, x0.y - x2.y);
            float2 a1 = make_float2(x1.x + x3.x, x1.y + x3.y);
            float2 d1 = make_float2(x1.x - x3.x, x1.y - x3.y);
            row[e0]     = make_float2(a0.x + a1.x, a0.y + a1.y);
            row[e0 + 1] = make_float2(a0.x - a1.x, a0.y - a1.y);
            row[e0 + 2] = make_float2(d0.x - d1.y, d0.y + d1.x);   // + i*d1
            row[e0 + 3] = make_float2(d0.x + d1.y, d0.y - d1.x);   // - i*d1
        }
    }
    __syncthreads();
}

// ---------------- row -> column map (mirror-closed block row sets) ----------------
__device__ __forceinline__ int c_of_row(int b, int r) {
    if (b == 0) {
        if (r < 8)  return r;               // 0..7
        if (r == 8) return 32768;           // self-mirrored
        return 65536 - (r - 8);             // r=9..15 -> 65535..65529
    }
    return (r < 8) ? (8 * b + r) : (65536 - 8 * b - (r - 8));
}

// ---------------- Fused: build W into LDS + IDFT over k3 (stride 65536) ----------------
__global__ __launch_bounds__(256, 4) void fused_build_fft_a(const float* __restrict__ el,
                                                            const float2* __restrict__ Q,
                                                            float2* __restrict__ out) {
    __shared__ float2 lds[16][257];
    __shared__ float c_s[25], s_s[25], T_s[24];
    int tid = threadIdx.x;
    if (tid < 25) {
        float e = el[tid];
        float shift1 = e * (1.0f / (float)(1u << tid));   // exact (pow2 scale)
        float sh2 = 1.0f - shift1;                        // THE float32 rounding
        float s = sh2 * (float)(1u << tid);               // exact
        float c = (float)(6.2831853071795864769 / (double)((1u << tid) + 1u));
        c_s[tid] = c;
        s_s[tid] = s;
        if (tid < 24) {
            float p  = (float)(1u << tid) * c;            // exact pow2 scale
            float th = p * s;                             // fl32
            float sn, cs; phase_sincos(th, &sn, &cs);
            T_s[tid] = cs;                                // terminal nyquist value
        }
    }
    __syncthreads();

    int b   = blockIdx.x;
    int r   = tid & 15;
    int k30 = tid >> 4;                                   // [0,16)
    int c   = c_of_row(b, r);
    // mirror row: self for the two self-mirrored columns, else r^8
    int rm  = (b == 0 && (r == 0 || r == 8)) ? r : (r ^ 8);

#pragma unroll 1
    for (int u = 0; u < 8; ++u) {
        int k3 = k30 + 16 * u;                            // [0,128)
        unsigned j = (unsigned)c + ((unsigned)k3 << 16);  // k value of lds[r][k3]
        if (b == 0 && r == 0 && k3 == 0) {
            // W[0] special + the self-paired k=2^23 bin (lands at lds[0][128])
            float p  = 16777216.0f * c_s[24];
            float th = p * s_s[24];
            float sn, cs; phase_sincos(th, &sn, &cs);
            const float sc = 1.0f / 33554432.0f;
            lds[0][0] = make_float2((1.0f + cs) * sc, (1.0f - cs) * sc);
            WPair w = chain_W(8388608u, c_s, s_s, T_s, Q);
            lds[0][128] = w.wk;
        } else {
            WPair w = chain_W(j, c_s, s_s, T_s, Q);
            lds[r][k3] = w.wk;
            int k3m = (b == 0 && r == 0) ? (256 - k3) : (255 - k3);
            lds[rm][k3m] = w.wmk;
        }
    }

    fft256x16_inv(lds, tid);

#pragma unroll
    for (int u = 0; u < 16; ++u) {
        int e = tid + 256 * u;
        int row = e & 15, p = e >> 4;
        int t3 = (int)(__brev((unsigned)p) >> 24);
        int cr = c_of_row(b, row);
        out[cr + (t3 << 16)] = lds[row][p];
    }
}

// ---------------- Stage B: twiddle e^{2*pi*i*t3*k2/65536}, IDFT over k2 (stride 256) ----------------
__global__ __launch_bounds__(256) void fft_stage_b(const float2* __restrict__ in,
                                                   float2* __restrict__ out) {
    __shared__ float2 lds[16][257];
    int tid = threadIdx.x;
    int wg  = blockIdx.x;
    int k1b = (wg & 15) * 16;
    int t3  = wg >> 4;
    const float tsc = TWOPI_F / 65536.0f;
    {
        int row = tid & 15;
        int k20 = tid >> 4;
        float sb, cb; __sincosf(tsc * (float)(t3 * k20), &sb, &cb);
        float ss, cs; __sincosf(tsc * (float)(t3 * 16), &ss, &cs);
        float2 w = make_float2(cb, sb);
#pragma unroll
        for (int u = 0; u < 16; ++u) {
            int k2 = k20 + 16 * u;
            float2 v = in[k1b + row + (k2 << 8) + (t3 << 16)];
            lds[row][k2] = make_float2(v.x * w.x - v.y * w.y, v.x * w.y + v.y * w.x);
            float nx = w.x * cs - w.y * ss;
            float ny = w.x * ss + w.y * cs;
            w = make_float2(nx, ny);
        }
    }
    fft256x16_inv(lds, tid);
#pragma unroll
    for (int u = 0; u < 16; ++u) {
        int e = tid + 256 * u;
        int row = e & 15, p = e >> 4;
        int t2 = (int)(__brev((unsigned)p) >> 24);
        out[k1b + row + (t2 << 8) + (t3 << 16)] = lds[row][p];
    }
}

// ---------------- Stage C: twiddle e^{2*pi*i*(t3+256*t2)*k1/2^24}, IDFT over k1 (stride 1) ----------------
__global__ __launch_bounds__(256) void fft_stage_c(const float2* __restrict__ in,
                                                   float2* __restrict__ out) {
    __shared__ float2 lds[16][257];
    int tid = threadIdx.x;
    int wg  = blockIdx.x;
    int t3b = (wg & 15) * 16;
    int t2  = wg >> 4;
    const float tsc = TWOPI_F / 16777216.0f;
    {
        int k1 = tid;
        int base = (t3b + (t2 << 8)) * k1;          // < 2^24, exact in float
        float sb, cb; __sincosf(tsc * (float)base, &sb, &cb);
        float ss, cs; __sincosf(tsc * (float)k1, &ss, &cs);
        float2 w = make_float2(cb, sb);
#pragma unroll
        for (int u = 0; u < 16; ++u) {
            float2 v = in[k1 + (t2 << 8) + ((t3b + u) << 16)];
            lds[u][k1] = make_float2(v.x * w.x - v.y * w.y, v.x * w.y + v.y * w.x);
            float nx = w.x * cs - w.y * ss;
            float ny = w.x * ss + w.y * cs;
            w = make_float2(nx, ny);
        }
    }
    fft256x16_inv(lds, tid);
#pragma unroll
    for (int u = 0; u < 16; ++u) {
        int e = tid + 256 * u;
        int r = e & 15, p = e >> 4;
        int t1 = (int)(__brev((unsigned)p) >> 24);
        out[(t3b + r) + (t2 << 8) + (t1 << 16)] = lds[r][p];
    }
}

extern "C" void kernel_launch(void* const* d_in, const int* in_sizes, int n_in,
                              void* d_out, int out_size, void* d_ws, size_t ws_size,
                              hipStream_t stream) {
    const float* el = (const float*)d_in[0];   // 25 floats
    float2* Gd = (float2*)d_out;               // out buffer doubles as complex ping-pong
    float2* Q  = (float2*)d_ws;                // Q table (2 MiB) lives in ws until stage B

    // build_q (ws) -> fusedA: (chains+FFT) -> out -> stageB: out->ws (clobbers Q, ok)
    // -> stageC: ws->out (final real signal)
    hipLaunchKernelGGL(build_q,          dim3(1024), dim3(256), 0, stream, el, Q);
    hipLaunchKernelGGL(fused_build_fft_a, dim3(4096), dim3(256), 0, stream, el, Q, Gd);
    hipLaunchKernelGGL(fft_stage_b,      dim3(4096), dim3(256), 0, stream, Gd, (float2*)d_ws);
    hipLaunchKernelGGL(fft_stage_c,      dim3(4096), dim3(256), 0, stream, (float2*)d_ws, Gd);
}

// Round 3
// 278.351 us; speedup vs baseline: 1.5262x; 1.0364x over previous
//
#include <hip/hip_runtime.h>

// HiearchicalFFTShiftModel: closed-form spectrum with EXACT emulation of the
// reference's complex64 phase quantization, + fused chain+FFT pass and two
// transpose-FFT passes over 2^24 complex points (c2r packing).
//
// Round-3 changes vs 288us:
//  1. fused_A chain hoisting (bit-exact): per thread k steps by 2^20, so the
//     stage-18/19 factors are identical across all 8 chains, stage 20 has 2
//     values, stage 21 has 4, and the Q residue (k mod 2^18) is constant ->
//     one Q load + factor tree. 72 -> 48 phase_sincos/thread, same float-op
//     order per k (bit-identical output).
//  2. Bijective XCD-chunked block swizzle on A/B/C (4096 = 8*512): consecutive
//     logical blocks co-reside on one XCD so A's 64B write halves merge into
//     full 128B lines in L2, and B/C's 128B-chunk streams stay dense per XCD.
//  3. Stages B/C: 16-deep register prefetch of the independent global loads
//     before the twiddle/LDS loop (raises MLP; loads no longer serialized
//     behind the rotation recurrence).

constexpr float PI_F    = 3.14159265358979323846f;
constexpr float TWOPI_F = 6.28318530717958647692f;
constexpr unsigned M24 = 1u << 24;

__device__ __forceinline__ void phase_sincos(float th, float* sn, float* cs) {
    // Accurate sin/cos of the float32 value th (|th| up to ~1.1e8):
    // reduce mod 2*pi in double, evaluate in float.
    double d = (double)th * 0.15915494309189533577;  // 1/(2*pi)
    d -= rint(d);                                    // frac in [-0.5, 0.5]
    float ang = (float)(d * 6.2831853071795864769);  // [-pi, pi]
    __sincosf(ang, sn, cs);
}

__device__ __forceinline__ float2 cmul(float2 a, float2 f) {
    // matches the reference op order: nr = Pr*cs - Pi*ssn; ni = Pr*ssn + Pi*cs
    return make_float2(a.x * f.x - a.y * f.y, a.x * f.y + a.y * f.x);
}

// chunked bijective XCD swizzle (nblocks divisible by 8)
__device__ __forceinline__ int xcd_swizzle(int b, int nblocks) {
    int chunk = nblocks >> 3;
    return (b & 7) * chunk + (b >> 3);
}

// ---------------- Kernel Q: partial chain product over stages 1..17 ----------------
// Q[r] = T_{ctz(r)} * prod_{i=ctz(r)+1}^{17} F_i(sd_i(r))   for r in [1, 2^18)
__global__ __launch_bounds__(256) void build_q(const float* __restrict__ el,
                                               float2* __restrict__ Q) {
    __shared__ float c_s[18], s_s[18], T_s[18];
    int tid = threadIdx.x;
    if (tid < 18) {
        float e = el[tid];
        float shift1 = e * (1.0f / (float)(1u << tid));   // exact (pow2 scale)
        float sh2 = 1.0f - shift1;                        // THE float32 rounding
        float s = sh2 * (float)(1u << tid);               // exact
        float c = (float)(6.2831853071795864769 / (double)((1u << tid) + 1u));
        c_s[tid] = c;
        s_s[tid] = s;
        float p  = (float)(1u << tid) * c;                // exact pow2 scale
        float th = p * s;                                 // fl32
        float sn, cs; phase_sincos(th, &sn, &cs);
        T_s[tid] = cs;                                    // terminal nyquist value
    }
    __syncthreads();

    unsigned r = blockIdx.x * 256u + (unsigned)tid;       // [0, 2^18)
    if (r == 0u) { Q[0] = make_float2(1.0f, 0.0f); return; }

    unsigned t = (unsigned)__builtin_ctz(r);              // t <= 17
    float Pr = T_s[t], Pi = 0.0f;

#pragma unroll
    for (int i = 1; i <= 17; ++i) {
        unsigned hi = 1u << i;
        int sd = (int)((r + hi) & (2u * hi - 1u)) - (int)hi;
        int K  = (i <= (int)t) ? 0 : (sd < 0 ? -sd : sd);
        float sgn = (sd < 0) ? -1.0f : 1.0f;
        float p  = (float)K * c_s[i];                     // fl32(K*c_i)
        float th = p * s_s[i];                            // fl32(.. * s_i)
        float sn, cs; phase_sincos(th, &sn, &cs);
        float ssn = sgn * sn;
        float nr = Pr * cs - Pi * ssn;
        float ni = Pr * ssn + Pi * cs;
        Pr = nr; Pi = ni;
    }
    Q[r] = make_float2(Pr, Pi);
}

// ---------------- chain factor for stage i at bin k (exact float sequence) ----------------
__device__ __forceinline__ float2 chain_factor(int i, unsigned k,
                                               const float* __restrict__ c_s,
                                               const float* __restrict__ s_s) {
    unsigned hi = 1u << i;
    int sd = (int)((k + hi) & (2u * hi - 1u)) - (int)hi;
    int K  = (sd < 0) ? -sd : sd;
    float sgn = (sd < 0) ? -1.0f : 1.0f;
    float p  = (float)K * c_s[i];                         // fl32(K*c_i)
    float th = p * s_s[i];                                // fl32(.. * s_i)
    float sn, cs; phase_sincos(th, &sn, &cs);
    return make_float2(cs, sgn * sn);
}

// ---------------- chain tail: level-24 factors + c2r pack ----------------
struct WPair { float2 wk, wmk; };

__device__ __forceinline__ WPair chain_tail(unsigned k, float Pr, float Pi,
                                            const float* __restrict__ c_s,
                                            const float* __restrict__ s_s) {
    const float sc = 1.0f / 33554432.0f;                  // 1/N
    unsigned mk = M24 - k;
    float thk = ((float)k  * c_s[24]) * s_s[24];
    float thm = ((float)mk * c_s[24]) * s_s[24];
    float snk, csk, snm, csm;
    phase_sincos(thk, &snk, &csk);
    phase_sincos(thm, &snm, &csm);

    float Skr = Pr * csk - Pi * snk;
    float Ski = Pr * snk + Pi * csk;
    float Smr = Pr * csm + Pi * snm;                      // conj(P) * e^{i*thm}
    float Smi = Pr * snm - Pi * csm;

    float Ar = Skr + Smr, Ai = Ski - Smi;
    float Br = Skr - Smr, Bi = Ski + Smi;
    float ang = (float)k * (TWOPI_F / 33554432.0f);
    float ts, tc; __sincosf(ang, &ts, &tc);
    float Cr = tc * Br - ts * Bi;
    float Ci = ts * Br + tc * Bi;

    WPair w;
    w.wk  = make_float2((Ar - Ci) * sc, (Ai + Cr) * sc);
    w.wmk = make_float2((Ar + Ci) * sc, (Cr - Ai) * sc);
    return w;
}

// ---------------- full chain (fallback for the b==0,r==0 row) ----------------
__device__ __forceinline__ WPair chain_W(unsigned k,
                                         const float* __restrict__ c_s,
                                         const float* __restrict__ s_s,
                                         const float* __restrict__ T_s,
                                         const float2* __restrict__ Q) {
    unsigned t = (unsigned)__builtin_ctz(k);              // t <= 23
    unsigned r = k & 0x3FFFFu;                            // k mod 2^18
    float Pr, Pi;
    if (r != 0u) {
        float2 q = Q[r];
        Pr = q.x; Pi = q.y;
    } else {
        Pr = T_s[t]; Pi = 0.0f;                           // t >= 18 here
    }
#pragma unroll
    for (int i = 18; i <= 23; ++i) {
        unsigned hi = 1u << i;
        int sd = (int)((k + hi) & (2u * hi - 1u)) - (int)hi;
        int K  = (i <= (int)t) ? 0 : (sd < 0 ? -sd : sd);
        float sgn = (sd < 0) ? -1.0f : 1.0f;
        float p  = (float)K * c_s[i];
        float th = p * s_s[i];
        float sn, cs; phase_sincos(th, &sn, &cs);
        float ssn = sgn * sn;
        float nr = Pr * cs - Pi * ssn;
        float ni = Pr * ssn + Pi * cs;
        Pr = nr; Pi = ni;
    }
    return chain_tail(k, Pr, Pi, c_s, s_s);
}

// ---------------- radix-4 butterfly (fused radix-2 level pair h, h/2) ----------------
__device__ __forceinline__ void bf4(float2* __restrict__ row, int e0, int d,
                                    float2 tw, float2 tw2) {
    float2 x0 = row[e0], x1 = row[e0 + d], x2 = row[e0 + 2*d], x3 = row[e0 + 3*d];
    float2 a0 = make_float2(x0.x + x2.x, x0.y + x2.y);
    float2 d0 = make_float2(x0.x - x2.x, x0.y - x2.y);
    float2 a1 = make_float2(x1.x + x3.x, x1.y + x3.y);
    float2 d1 = make_float2(x1.x - x3.x, x1.y - x3.y);
    float2 a2 = make_float2(d0.x * tw.x - d0.y * tw.y,  d0.x * tw.y + d0.y * tw.x);
    float2 a3 = make_float2(-d1.x * tw.y - d1.y * tw.x, d1.x * tw.x - d1.y * tw.y);
    row[e0]       = make_float2(a0.x + a1.x, a0.y + a1.y);
    float2 u1 = make_float2(a0.x - a1.x, a0.y - a1.y);
    row[e0 + d]   = make_float2(u1.x * tw2.x - u1.y * tw2.y, u1.x * tw2.y + u1.y * tw2.x);
    row[e0 + 2*d] = make_float2(a2.x + a3.x, a2.y + a3.y);
    float2 u3 = make_float2(a2.x - a3.x, a2.y - a3.y);
    row[e0 + 3*d] = make_float2(u3.x * tw2.x - u3.y * tw2.y, u3.x * tw2.y + u3.y * tw2.x);
}

// ---------------- shared radix-4 in-place DIF inverse FFT over 16 rows x 256 ----------------
// Output lands bit-reversed within each row: position p holds X[brev8(p)].
__device__ __forceinline__ void fft256x16_inv(float2 (*lds)[257], int tid) {
    // step0: h=128, d=64.
    {
        int j2 = tid & 63;
        float s, c; __sincosf((PI_F / 128.0f) * (float)j2, &s, &c);
        float2 tw  = make_float2(c, s);
        float2 tw2 = make_float2(c * c - s * s, 2.0f * c * s);
        __syncthreads();
#pragma unroll
        for (int v = 0; v < 4; ++v) {
            int row = (tid >> 6) + 4 * v;
            bf4(lds[row], j2, 64, tw, tw2);
        }
    }
    // step1: h=32, d=16.
    {
        int rowb = tid & 15;
        int j2   = tid >> 4;
        float s, c; __sincosf((PI_F / 32.0f) * (float)j2, &s, &c);
        float2 tw  = make_float2(c, s);
        float2 tw2 = make_float2(c * c - s * s, 2.0f * c * s);
        __syncthreads();
#pragma unroll
        for (int v = 0; v < 4; ++v) {
            bf4(lds[rowb], 64 * v + j2, 16, tw, tw2);
        }
    }
    // step2: h=8, d=4.
    {
        int rowb = tid & 15;
        int j2   = tid >> 6;
        int bbl  = (tid >> 4) & 3;
        float s, c; __sincosf((PI_F / 8.0f) * (float)j2, &s, &c);
        float2 tw  = make_float2(c, s);
        float2 tw2 = make_float2(c * c - s * s, 2.0f * c * s);
        __syncthreads();
#pragma unroll
        for (int v = 0; v < 4; ++v) {
            int bb = bbl + 4 * v;
            bf4(lds[rowb], 16 * bb + j2, 4, tw, tw2);
        }
    }
    // step3: h=2, d=1.  all twiddles trivial.
    {
        int rowb = tid & 15;
        int bbl  = tid >> 4;
        __syncthreads();
#pragma unroll
        for (int v = 0; v < 4; ++v) {
            int e0 = 4 * (bbl + 16 * v);
            float2* row = lds[rowb];
            float2 x0 = row[e0], x1 = row[e0 + 1], x2 = row[e0 + 2], x3 = row[e0 + 3];
            float2 a0 = make_float2(x0.x + x2.x, x0.y + x2.y);
            float2 d0 = make_float2(x0.x - x2.x, x0.y - x2.y);
            float2 a1 = make_float2(x1.x + x3.x, x1.y + x3.y);
            float2 d1 = make_float2(x1.x - x3.x, x1.y - x3.y);
            row[e0]     = make_float2(a0.x + a1.x, a0.y + a1.y);
            row[e0 + 1] = make_float2(a0.x - a1.x, a0.y - a1.y);
            row[e0 + 2] = make_float2(d0.x - d1.y, d0.y + d1.x);   // + i*d1
            row[e0 + 3] = make_float2(d0.x + d1.y, d0.y - d1.x);   // - i*d1
        }
    }
    __syncthreads();
}

// ---------------- row -> column map (mirror-closed block row sets) ----------------
__device__ __forceinline__ int c_of_row(int b, int r) {
    if (b == 0) {
        if (r < 8)  return r;               // 0..7
        if (r == 8) return 32768;           // self-mirrored
        return 65536 - (r - 8);             // r=9..15 -> 65535..65529
    }
    return (r < 8) ? (8 * b + r) : (65536 - 8 * b - (r - 8));
}

// ---------------- Fused: build W into LDS + IDFT over k3 (stride 65536) ----------------
__global__ __launch_bounds__(256, 4) void fused_build_fft_a(const float* __restrict__ el,
                                                            const float2* __restrict__ Q,
                                                            float2* __restrict__ out) {
    __shared__ float2 lds[16][257];
    __shared__ float c_s[25], s_s[25], T_s[24];
    int tid = threadIdx.x;
    if (tid < 25) {
        float e = el[tid];
        float shift1 = e * (1.0f / (float)(1u << tid));   // exact (pow2 scale)
        float sh2 = 1.0f - shift1;                        // THE float32 rounding
        float s = sh2 * (float)(1u << tid);               // exact
        float c = (float)(6.2831853071795864769 / (double)((1u << tid) + 1u));
        c_s[tid] = c;
        s_s[tid] = s;
        if (tid < 24) {
            float p  = (float)(1u << tid) * c;            // exact pow2 scale
            float th = p * s;                             // fl32
            float sn, cs; phase_sincos(th, &sn, &cs);
            T_s[tid] = cs;                                // terminal nyquist value
        }
    }
    __syncthreads();

    int b   = xcd_swizzle(blockIdx.x, 4096);
    int r   = tid & 15;
    int k30 = tid >> 4;                                   // [0,16)
    int c   = c_of_row(b, r);
    int rm  = (b == 0 && (r == 0 || r == 8)) ? r : (r ^ 8);

    if (b == 0 && r == 0) {
        // self-mirrored c=0 row: full chains (t can exceed 17 here)
#pragma unroll 1
        for (int u = 0; u < 8; ++u) {
            int k3 = k30 + 16 * u;
            if (k3 == 0) {
                float p  = 16777216.0f * c_s[24];
                float th = p * s_s[24];
                float sn, cs; phase_sincos(th, &sn, &cs);
                const float sc = 1.0f / 33554432.0f;
                lds[0][0] = make_float2((1.0f + cs) * sc, (1.0f - cs) * sc);
                WPair w = chain_W(8388608u, c_s, s_s, T_s, Q);
                lds[0][128] = w.wk;
            } else {
                unsigned j = (unsigned)k3 << 16;
                WPair w = chain_W(j, c_s, s_s, T_s, Q);
                lds[0][k3] = w.wk;
                lds[0][256 - k3] = w.wmk;
            }
        }
    } else {
        // hoisted factor tree: k = kbase + u*2^20, u = 0..7.
        // t = ctz(k) <= 15 always (c in [1,65535]) -> no identity guards,
        // and k mod 2^18 = c + (k30&3)*2^16 is constant across u.
        unsigned kbase = (unsigned)c + ((unsigned)k30 << 16);
        unsigned rres  = kbase & 0x3FFFFu;                // nonzero
        float2 P1 = Q[rres];
        P1 = cmul(P1, chain_factor(18, kbase, c_s, s_s)); // same for all u
        P1 = cmul(P1, chain_factor(19, kbase, c_s, s_s)); // same for all u
        float2 P2[2], P3[4];
#pragma unroll
        for (int j = 0; j < 2; ++j)
            P2[j] = cmul(P1, chain_factor(20, kbase + ((unsigned)j << 20), c_s, s_s));
#pragma unroll
        for (int j = 0; j < 4; ++j)
            P3[j] = cmul(P2[j & 1], chain_factor(21, kbase + ((unsigned)j << 20), c_s, s_s));

#pragma unroll 1
        for (int u = 0; u < 8; ++u) {
            int k3 = k30 + 16 * u;
            unsigned k = kbase + ((unsigned)u << 20);
            float2 P = cmul(P3[u & 3], chain_factor(22, k, c_s, s_s));
            P = cmul(P, chain_factor(23, k, c_s, s_s));
            WPair w = chain_tail(k, P.x, P.y, c_s, s_s);
            lds[r][k3] = w.wk;
            lds[rm][255 - k3] = w.wmk;
        }
    }

    fft256x16_inv(lds, tid);

#pragma unroll
    for (int u = 0; u < 16; ++u) {
        int e = tid + 256 * u;
        int row = e & 15, p = e >> 4;
        int t3 = (int)(__brev((unsigned)p) >> 24);
        int cr = c_of_row(b, row);
        out[cr + (t3 << 16)] = lds[row][p];
    }
}

// ---------------- Stage B: twiddle e^{2*pi*i*t3*k2/65536}, IDFT over k2 (stride 256) ----------------
__global__ __launch_bounds__(256, 4) void fft_stage_b(const float2* __restrict__ in,
                                                      float2* __restrict__ out) {
    __shared__ float2 lds[16][257];
    int tid = threadIdx.x;
    int wg  = xcd_swizzle(blockIdx.x, 4096);
    int k1b = (wg & 15) * 16;
    int t3  = wg >> 4;
    const float tsc = TWOPI_F / 65536.0f;
    {
        int row = tid & 15;
        int k20 = tid >> 4;
        const float2* src = in + (k1b + row + (k20 << 8) + (t3 << 16));
        float2 vbuf[16];
#pragma unroll
        for (int u = 0; u < 16; ++u) vbuf[u] = src[u << 12];   // stride 16<<8
        float sb, cb; __sincosf(tsc * (float)(t3 * k20), &sb, &cb);
        float ss, cs; __sincosf(tsc * (float)(t3 * 16), &ss, &cs);
        float2 w = make_float2(cb, sb);
#pragma unroll
        for (int u = 0; u < 16; ++u) {
            int k2 = k20 + 16 * u;
            float2 v = vbuf[u];
            lds[row][k2] = make_float2(v.x * w.x - v.y * w.y, v.x * w.y + v.y * w.x);
            float nx = w.x * cs - w.y * ss;
            float ny = w.x * ss + w.y * cs;
            w = make_float2(nx, ny);
        }
    }
    fft256x16_inv(lds, tid);
#pragma unroll
    for (int u = 0; u < 16; ++u) {
        int e = tid + 256 * u;
        int row = e & 15, p = e >> 4;
        int t2 = (int)(__brev((unsigned)p) >> 24);
        out[k1b + row + (t2 << 8) + (t3 << 16)] = lds[row][p];
    }
}

// ---------------- Stage C: twiddle e^{2*pi*i*(t3+256*t2)*k1/2^24}, IDFT over k1 (stride 1) ----------------
__global__ __launch_bounds__(256, 4) void fft_stage_c(const float2* __restrict__ in,
                                                      float2* __restrict__ out) {
    __shared__ float2 lds[16][257];
    int tid = threadIdx.x;
    int wg  = xcd_swizzle(blockIdx.x, 4096);
    int t3b = (wg & 15) * 16;
    int t2  = wg >> 4;
    const float tsc = TWOPI_F / 16777216.0f;
    {
        int k1 = tid;
        const float2* src = in + (k1 + (t2 << 8) + (t3b << 16));
        float2 vbuf[16];
#pragma unroll
        for (int u = 0; u < 16; ++u) vbuf[u] = src[u << 16];
        int base = (t3b + (t2 << 8)) * k1;          // < 2^24, exact in float
        float sb, cb; __sincosf(tsc * (float)base, &sb, &cb);
        float ss, cs; __sincosf(tsc * (float)k1, &ss, &cs);
        float2 w = make_float2(cb, sb);
#pragma unroll
        for (int u = 0; u < 16; ++u) {
            float2 v = vbuf[u];
            lds[u][k1] = make_float2(v.x * w.x - v.y * w.y, v.x * w.y + v.y * w.x);
            float nx = w.x * cs - w.y * ss;
            float ny = w.x * ss + w.y * cs;
            w = make_float2(nx, ny);
        }
    }
    fft256x16_inv(lds, tid);
#pragma unroll
    for (int u = 0; u < 16; ++u) {
        int e = tid + 256 * u;
        int r = e & 15, p = e >> 4;
        int t1 = (int)(__brev((unsigned)p) >> 24);
        out[(t3b + r) + (t2 << 8) + (t1 << 16)] = lds[r][p];
    }
}

extern "C" void kernel_launch(void* const* d_in, const int* in_sizes, int n_in,
                              void* d_out, int out_size, void* d_ws, size_t ws_size,
                              hipStream_t stream) {
    const float* el = (const float*)d_in[0];   // 25 floats
    float2* Gd = (float2*)d_out;               // out buffer doubles as complex ping-pong
    float2* Q  = (float2*)d_ws;                // Q table (2 MiB) lives in ws until stage B

    // build_q (ws) -> fusedA: (chains+FFT) -> out -> stageB: out->ws (clobbers Q, ok)
    // -> stageC: ws->out (final real signal)
    hipLaunchKernelGGL(build_q,           dim3(1024), dim3(256), 0, stream, el, Q);
    hipLaunchKernelGGL(fused_build_fft_a, dim3(4096), dim3(256), 0, stream, el, Q, Gd);
    hipLaunchKernelGGL(fft_stage_b,       dim3(4096), dim3(256), 0, stream, Gd, (float2*)d_ws);
    hipLaunchKernelGGL(fft_stage_c,       dim3(4096), dim3(256), 0, stream, (float2*)d_ws, Gd);
}

// Round 4
// 270.856 us; speedup vs baseline: 1.5685x; 1.0277x over previous
//
#include <hip/hip_runtime.h>

// HiearchicalFFTShiftModel: closed-form spectrum with EXACT emulation of the
// reference's complex64 phase quantization, + fused chain+FFT pass and two
// transpose-FFT passes over 2^24 complex points (c2r packing).
//
// Round-4 change vs 278us: replace the 8-level LDS radix-4 FFT ladder
// (5 barriers, 80+80 LDS b64 ops/thread) with a radix-16^2 REGISTER FFT:
//   256-pt IDFT = [16-pt IDFT in regs over n1] * w256^{n2*K1} -> LDS
//   transpose -> [16-pt IDFT in regs over n2], natural-order output.
// B: load(stride-16 = phase-1 set) -> regs -> 1 barrier total.
// A/C: one raw staging pass in LDS (layout forces it) -> 2 barriers.
// 16-pt DFTs use hard-coded w16 constants (no sincos); z-twiddle is
// 1 sincos + 15-step rotation recurrence. All LDS patterns uniform
// 4 lanes/bank-pair (conflict-free floor) with the [16][257] padding.
// W-chain arithmetic unchanged (bit-exact vs round-3).

constexpr float TWOPI_F = 6.28318530717958647692f;
constexpr unsigned M24 = 1u << 24;

__device__ __forceinline__ void phase_sincos(float th, float* sn, float* cs) {
    double d = (double)th * 0.15915494309189533577;  // 1/(2*pi)
    d -= rint(d);                                    // frac in [-0.5, 0.5]
    float ang = (float)(d * 6.2831853071795864769);  // [-pi, pi]
    __sincosf(ang, sn, cs);
}

__device__ __forceinline__ float2 cmul(float2 a, float2 f) {
    return make_float2(a.x * f.x - a.y * f.y, a.x * f.y + a.y * f.x);
}
__device__ __forceinline__ float2 caddf(float2 a, float2 b) { return make_float2(a.x + b.x, a.y + b.y); }
__device__ __forceinline__ float2 csubf(float2 a, float2 b) { return make_float2(a.x - b.x, a.y - b.y); }
__device__ __forceinline__ float2 cmulw(float2 a, float c, float s) {
    return make_float2(a.x * c - a.y * s, a.x * s + a.y * c);
}

// chunked bijective XCD swizzle (nblocks divisible by 8)
__device__ __forceinline__ int xcd_swizzle(int b, int nblocks) {
    int chunk = nblocks >> 3;
    return (b & 7) * chunk + (b >> 3);
}

// ---------------- in-register 16-point inverse DFT (natural in/out) ----------------
// y[K] = sum_n x[n] e^{+2pi i nK/16}; radix-4 x 2 with hard-coded twiddles.
__device__ __forceinline__ void fft16_inv(float2* v) {
    const float C1 = 0.92387953251128675613f;   // cos(pi/8)
    const float S1 = 0.38268343236508977173f;   // sin(pi/8)
    const float R2 = 0.70710678118654752440f;   // sqrt(2)/2
    float2 h[16];
#pragma unroll
    for (int b = 0; b < 4; ++b) {
        float2 s02 = caddf(v[b], v[b + 8]);
        float2 d02 = csubf(v[b], v[b + 8]);
        float2 s13 = caddf(v[b + 4], v[b + 12]);
        float2 d13 = csubf(v[b + 4], v[b + 12]);
        float2 id13 = make_float2(-d13.y, d13.x);          // i*d13
        h[4 * b + 0] = caddf(s02, s13);
        h[4 * b + 1] = caddf(d02, id13);
        h[4 * b + 2] = csubf(s02, s13);
        h[4 * b + 3] = csubf(d02, id13);
    }
    // h[4b+K1] *= w16^{b*K1}
    h[5]  = cmulw(h[5],  C1,  S1);                               // w1
    h[6]  = make_float2(R2 * (h[6].x - h[6].y),  R2 * (h[6].x + h[6].y));   // w2
    h[7]  = cmulw(h[7],  S1,  C1);                               // w3
    h[9]  = make_float2(R2 * (h[9].x - h[9].y),  R2 * (h[9].x + h[9].y));   // w2
    h[10] = make_float2(-h[10].y, h[10].x);                      // w4 = i
    h[11] = cmulw(h[11], -R2, R2);                               // w6 = i*w2
    h[13] = cmulw(h[13], S1,  C1);                               // w3
    h[14] = cmulw(h[14], -R2, R2);                               // w6
    h[15] = cmulw(h[15], -C1, -S1);                              // w9 = -w1
#pragma unroll
    for (int K1 = 0; K1 < 4; ++K1) {
        float2 a = h[K1], bb = h[4 + K1], cc = h[8 + K1], dd = h[12 + K1];
        float2 sac = caddf(a, cc), dac = csubf(a, cc);
        float2 sbd = caddf(bb, dd), dbd = csubf(bb, dd);
        float2 idbd = make_float2(-dbd.y, dbd.x);
        v[K1]      = caddf(sac, sbd);
        v[K1 + 4]  = caddf(dac, idbd);
        v[K1 + 8]  = csubf(sac, sbd);
        v[K1 + 12] = csubf(dac, idbd);
    }
}

// z-twiddle: v[K1] *= e^{+2pi i q K1/256}, K1 = 0..15 (1 sincos + recurrence)
__device__ __forceinline__ void ztwiddle(float2* v, int q) {
    float ss, cc;
    __sincosf((TWOPI_F / 256.0f) * (float)q, &ss, &cc);
    float2 w = make_float2(1.0f, 0.0f), stp = make_float2(cc, ss);
#pragma unroll
    for (int K1 = 0; K1 < 16; ++K1) {
        v[K1] = cmul(v[K1], w);
        w = cmul(w, stp);
    }
}

// ---------------- Kernel Q: partial chain product over stages 1..17 ----------------
__global__ __launch_bounds__(256) void build_q(const float* __restrict__ el,
                                               float2* __restrict__ Q) {
    __shared__ float c_s[18], s_s[18], T_s[18];
    int tid = threadIdx.x;
    if (tid < 18) {
        float e = el[tid];
        float shift1 = e * (1.0f / (float)(1u << tid));
        float sh2 = 1.0f - shift1;                        // THE float32 rounding
        float s = sh2 * (float)(1u << tid);
        float c = (float)(6.2831853071795864769 / (double)((1u << tid) + 1u));
        c_s[tid] = c;
        s_s[tid] = s;
        float p  = (float)(1u << tid) * c;
        float th = p * s;
        float sn, cs; phase_sincos(th, &sn, &cs);
        T_s[tid] = cs;
    }
    __syncthreads();

    unsigned r = blockIdx.x * 256u + (unsigned)tid;       // [0, 2^18)
    if (r == 0u) { Q[0] = make_float2(1.0f, 0.0f); return; }

    unsigned t = (unsigned)__builtin_ctz(r);              // t <= 17
    float Pr = T_s[t], Pi = 0.0f;

#pragma unroll
    for (int i = 1; i <= 17; ++i) {
        unsigned hi = 1u << i;
        int sd = (int)((r + hi) & (2u * hi - 1u)) - (int)hi;
        int K  = (i <= (int)t) ? 0 : (sd < 0 ? -sd : sd);
        float sgn = (sd < 0) ? -1.0f : 1.0f;
        float p  = (float)K * c_s[i];
        float th = p * s_s[i];
        float sn, cs; phase_sincos(th, &sn, &cs);
        float ssn = sgn * sn;
        float nr = Pr * cs - Pi * ssn;
        float ni = Pr * ssn + Pi * cs;
        Pr = nr; Pi = ni;
    }
    Q[r] = make_float2(Pr, Pi);
}

// ---------------- chain factor for stage i at bin k (exact float sequence) ----------------
__device__ __forceinline__ float2 chain_factor(int i, unsigned k,
                                               const float* __restrict__ c_s,
                                               const float* __restrict__ s_s) {
    unsigned hi = 1u << i;
    int sd = (int)((k + hi) & (2u * hi - 1u)) - (int)hi;
    int K  = (sd < 0) ? -sd : sd;
    float sgn = (sd < 0) ? -1.0f : 1.0f;
    float p  = (float)K * c_s[i];
    float th = p * s_s[i];
    float sn, cs; phase_sincos(th, &sn, &cs);
    return make_float2(cs, sgn * sn);
}

// ---------------- chain tail: level-24 factors + c2r pack ----------------
struct WPair { float2 wk, wmk; };

__device__ __forceinline__ WPair chain_tail(unsigned k, float Pr, float Pi,
                                            const float* __restrict__ c_s,
                                            const float* __restrict__ s_s) {
    const float sc = 1.0f / 33554432.0f;                  // 1/N
    unsigned mk = M24 - k;
    float thk = ((float)k  * c_s[24]) * s_s[24];
    float thm = ((float)mk * c_s[24]) * s_s[24];
    float snk, csk, snm, csm;
    phase_sincos(thk, &snk, &csk);
    phase_sincos(thm, &snm, &csm);

    float Skr = Pr * csk - Pi * snk;
    float Ski = Pr * snk + Pi * csk;
    float Smr = Pr * csm + Pi * snm;                      // conj(P) * e^{i*thm}
    float Smi = Pr * snm - Pi * csm;

    float Ar = Skr + Smr, Ai = Ski - Smi;
    float Br = Skr - Smr, Bi = Ski + Smi;
    float ang = (float)k * (TWOPI_F / 33554432.0f);
    float ts, tc; __sincosf(ang, &ts, &tc);
    float Cr = tc * Br - ts * Bi;
    float Ci = ts * Br + tc * Bi;

    WPair w;
    w.wk  = make_float2((Ar - Ci) * sc, (Ai + Cr) * sc);
    w.wmk = make_float2((Ar + Ci) * sc, (Cr - Ai) * sc);
    return w;
}

// ---------------- full chain (fallback for the b==0 special rows) ----------------
__device__ __forceinline__ WPair chain_W(unsigned k,
                                         const float* __restrict__ c_s,
                                         const float* __restrict__ s_s,
                                         const float* __restrict__ T_s,
                                         const float2* __restrict__ Q) {
    unsigned t = (unsigned)__builtin_ctz(k);              // t <= 23
    unsigned r = k & 0x3FFFFu;
    float Pr, Pi;
    if (r != 0u) {
        float2 q = Q[r];
        Pr = q.x; Pi = q.y;
    } else {
        Pr = T_s[t]; Pi = 0.0f;
    }
#pragma unroll
    for (int i = 18; i <= 23; ++i) {
        unsigned hi = 1u << i;
        int sd = (int)((k + hi) & (2u * hi - 1u)) - (int)hi;
        int K  = (i <= (int)t) ? 0 : (sd < 0 ? -sd : sd);
        float sgn = (sd < 0) ? -1.0f : 1.0f;
        float p  = (float)K * c_s[i];
        float th = p * s_s[i];
        float sn, cs; phase_sincos(th, &sn, &cs);
        float ssn = sgn * sn;
        float nr = Pr * cs - Pi * ssn;
        float ni = Pr * ssn + Pi * cs;
        Pr = nr; Pi = ni;
    }
    return chain_tail(k, Pr, Pi, c_s, s_s);
}

// ---------------- row -> column map (mirror-closed block row sets) ----------------
__device__ __forceinline__ int c_of_row(int b, int r) {
    if (b == 0) {
        if (r < 8)  return r;               // 0..7
        if (r == 8) return 32768;           // self-mirrored
        return 65536 - (r - 8);             // r=9..15 -> 65535..65529
    }
    return (r < 8) ? (8 * b + r) : (65536 - 8 * b - (r - 8));
}

// ---------------- Fused: build W (raw in LDS) + radix-16^2 IDFT over k3 ----------------
__global__ __launch_bounds__(256, 3) void fused_build_fft_a(const float* __restrict__ el,
                                                            const float2* __restrict__ Q,
                                                            float2* __restrict__ out) {
    __shared__ float2 lds[16][257];
    __shared__ float c_s[25], s_s[25], T_s[24];
    int tid = threadIdx.x;
    if (tid < 25) {
        float e = el[tid];
        float shift1 = e * (1.0f / (float)(1u << tid));
        float sh2 = 1.0f - shift1;                        // THE float32 rounding
        float s = sh2 * (float)(1u << tid);
        float c = (float)(6.2831853071795864769 / (double)((1u << tid) + 1u));
        c_s[tid] = c;
        s_s[tid] = s;
        if (tid < 24) {
            float p  = (float)(1u << tid) * c;
            float th = p * s;
            float sn, cs; phase_sincos(th, &sn, &cs);
            T_s[tid] = cs;
        }
    }
    __syncthreads();

    int b = xcd_swizzle(blockIdx.x, 4096);
    int r = tid & 15;
    int q = tid >> 4;                                     // [0,16)
    int c = c_of_row(b, r);
    int rm = (b == 0 && (r == 0 || r == 8)) ? r : (r ^ 8);

    if (b == 0 && r == 0) {
        // self-mirrored c=0 row: full chains
#pragma unroll 1
        for (int u = 0; u < 8; ++u) {
            int k3 = q + 16 * u;
            if (k3 == 0) {
                float p  = 16777216.0f * c_s[24];
                float th = p * s_s[24];
                float sn, cs; phase_sincos(th, &sn, &cs);
                const float sc = 1.0f / 33554432.0f;
                lds[0][0] = make_float2((1.0f + cs) * sc, (1.0f - cs) * sc);
                WPair w = chain_W(8388608u, c_s, s_s, T_s, Q);
                lds[0][128] = w.wk;
            } else {
                unsigned j = (unsigned)k3 << 16;
                WPair w = chain_W(j, c_s, s_s, T_s, Q);
                lds[0][k3] = w.wk;
                lds[0][256 - k3] = w.wmk;
            }
        }
    } else {
        // hoisted factor tree: k = kbase + u*2^20, u = 0..7 (bit-exact per k)
        unsigned kbase = (unsigned)c + ((unsigned)q << 16);
        unsigned rres  = kbase & 0x3FFFFu;                // nonzero
        float2 P1 = Q[rres];
        P1 = cmul(P1, chain_factor(18, kbase, c_s, s_s));
        P1 = cmul(P1, chain_factor(19, kbase, c_s, s_s));
        float2 P2[2], P3[4];
#pragma unroll
        for (int j = 0; j < 2; ++j)
            P2[j] = cmul(P1, chain_factor(20, kbase + ((unsigned)j << 20), c_s, s_s));
#pragma unroll
        for (int j = 0; j < 4; ++j)
            P3[j] = cmul(P2[j & 1], chain_factor(21, kbase + ((unsigned)j << 20), c_s, s_s));

#pragma unroll 1
        for (int u = 0; u < 8; ++u) {
            int k3 = q + 16 * u;
            unsigned k = kbase + ((unsigned)u << 20);
            float2 P = cmul(P3[u & 3], chain_factor(22, k, c_s, s_s));
            P = cmul(P, chain_factor(23, k, c_s, s_s));
            WPair w = chain_tail(k, P.x, P.y, c_s, s_s);
            lds[r][k3] = w.wk;
            lds[rm][255 - k3] = w.wmk;
        }
    }
    __syncthreads();

    // phase 1: thread (r,q) owns column n2=q of row r
    float2 v[16];
#pragma unroll
    for (int n1 = 0; n1 < 16; ++n1) v[n1] = lds[r][q + 16 * n1];
    fft16_inv(v);
    ztwiddle(v, q);
#pragma unroll
    for (int K1 = 0; K1 < 16; ++K1) lds[r][K1 * 16 + q] = v[K1];   // own slot set
    __syncthreads();

    // phase 2: thread (r,q) owns K1=q; output t3 = q + 16*K2 (natural order)
#pragma unroll
    for (int n2 = 0; n2 < 16; ++n2) v[n2] = lds[r][q * 16 + n2];
    fft16_inv(v);
#pragma unroll
    for (int K2 = 0; K2 < 16; ++K2)
        out[c + ((q + 16 * K2) << 16)] = v[K2];
}

// ---------------- Stage B: twiddle + radix-16^2 IDFT over k2 (stride 256) ----------------
__global__ __launch_bounds__(256, 3) void fft_stage_b(const float2* __restrict__ in,
                                                      float2* __restrict__ out) {
    __shared__ float2 lds[16][257];
    int tid = threadIdx.x;
    int wg  = xcd_swizzle(blockIdx.x, 4096);
    int k1b = (wg & 15) * 16;
    int t3  = wg >> 4;
    const float tsc = TWOPI_F / 65536.0f;
    int row = tid & 15;
    int q   = tid >> 4;                                   // n2 = q; loads ARE the phase-1 set

    float2 v[16];
    const float2* src = in + (k1b + row + (q << 8) + (t3 << 16));
#pragma unroll
    for (int u = 0; u < 16; ++u) v[u] = src[u << 12];     // k2 = q + 16u

    {   // inter-stage twiddle e^{+i tsc t3 k2}
        float sb, cb; __sincosf(tsc * (float)(t3 * q), &sb, &cb);
        float ssx, csx; __sincosf(tsc * (float)(t3 * 16), &ssx, &csx);
        float2 w = make_float2(cb, sb), stp = make_float2(csx, ssx);
#pragma unroll
        for (int u = 0; u < 16; ++u) {
            v[u] = cmul(v[u], w);
            w = cmul(w, stp);
        }
    }
    fft16_inv(v);
    ztwiddle(v, q);
#pragma unroll
    for (int K1 = 0; K1 < 16; ++K1) lds[row][K1 * 16 + q] = v[K1];
    __syncthreads();

#pragma unroll
    for (int n2 = 0; n2 < 16; ++n2) v[n2] = lds[row][q * 16 + n2];
    fft16_inv(v);
#pragma unroll
    for (int K2 = 0; K2 < 16; ++K2)
        out[k1b + row + ((q + 16 * K2) << 8) + (t3 << 16)] = v[K2];
}

// ---------------- Stage C: twiddle + radix-16^2 IDFT over k1 (stride 1) ----------------
__global__ __launch_bounds__(256, 3) void fft_stage_c(const float2* __restrict__ in,
                                                      float2* __restrict__ out) {
    __shared__ float2 lds[16][257];
    int tid = threadIdx.x;
    int wg  = xcd_swizzle(blockIdx.x, 4096);
    int t3b = (wg & 15) * 16;
    int t2  = wg >> 4;
    const float tsc = TWOPI_F / 16777216.0f;

    {   // load one k1 column across 16 rows, twiddle, raw-stage to LDS
        int k1 = tid;
        const float2* src = in + (k1 + (t2 << 8) + (t3b << 16));
        float2 vb[16];
#pragma unroll
        for (int u = 0; u < 16; ++u) vb[u] = src[u << 16];
        int base = (t3b + (t2 << 8)) * k1;                // < 2^24, exact in float
        float sb, cb; __sincosf(tsc * (float)base, &sb, &cb);
        float ssx, csx; __sincosf(tsc * (float)k1, &ssx, &csx);
        float2 w = make_float2(cb, sb), stp = make_float2(csx, ssx);
#pragma unroll
        for (int u = 0; u < 16; ++u) {
            lds[u][k1] = cmul(vb[u], w);
            w = cmul(w, stp);
        }
    }
    __syncthreads();

    int rr = tid & 15;
    int q  = tid >> 4;
    float2 v[16];
#pragma unroll
    for (int n1 = 0; n1 < 16; ++n1) v[n1] = lds[rr][q + 16 * n1];
    fft16_inv(v);
    ztwiddle(v, q);
#pragma unroll
    for (int K1 = 0; K1 < 16; ++K1) lds[rr][K1 * 16 + q] = v[K1];  // own slot set
    __syncthreads();

#pragma unroll
    for (int n2 = 0; n2 < 16; ++n2) v[n2] = lds[rr][q * 16 + n2];
    fft16_inv(v);
#pragma unroll
    for (int K2 = 0; K2 < 16; ++K2)
        out[(t3b + rr) + (t2 << 8) + ((q + 16 * K2) << 16)] = v[K2];
}

extern "C" void kernel_launch(void* const* d_in, const int* in_sizes, int n_in,
                              void* d_out, int out_size, void* d_ws, size_t ws_size,
                              hipStream_t stream) {
    const float* el = (const float*)d_in[0];   // 25 floats
    float2* Gd = (float2*)d_out;               // out buffer doubles as complex ping-pong
    float2* Q  = (float2*)d_ws;                // Q table (2 MiB) lives in ws until stage B

    // build_q (ws) -> fusedA: (chains+FFT) -> out -> stageB: out->ws (clobbers Q, ok)
    // -> stageC: ws->out (final real signal)
    hipLaunchKernelGGL(build_q,           dim3(1024), dim3(256), 0, stream, el, Q);
    hipLaunchKernelGGL(fused_build_fft_a, dim3(4096), dim3(256), 0, stream, el, Q, Gd);
    hipLaunchKernelGGL(fft_stage_b,       dim3(4096), dim3(256), 0, stream, Gd, (float2*)d_ws);
    hipLaunchKernelGGL(fft_stage_c,       dim3(4096), dim3(256), 0, stream, (float2*)d_ws, Gd);
}